// Round 11
// baseline (123.889 us; speedup 1.0000x reference)
//
#include <hip/hip_runtime.h>
#include <stdint.h>
#include <math.h>

#define BB 512
#define RR 20
#define LL 50
#define DD 64
#define PP 2
#define KK 10
#define IN_DIM 256   // 2*P*D
#define VV 50000
#define NEBLK 1280   // embed blocks (16 reviews each)
#define NTBLK 782    // table-GEMM blocks (64 words each)

// ---------------- threefry2x32 (bit-exact JAX) ----------------
__device__ __forceinline__ uint32_t rotl32(uint32_t v, int d) {
  return (v << d) | (v >> (32 - d));
}

__device__ __forceinline__ void tf2x32(uint32_t k0, uint32_t k1,
                                       uint32_t x0, uint32_t x1,
                                       uint32_t& o0, uint32_t& o1) {
  uint32_t ks0 = k0, ks1 = k1, ks2 = k0 ^ k1 ^ 0x1BD11BDAu;
  x0 += ks0; x1 += ks1;
#define TF_RND(r) { x0 += x1; x1 = rotl32(x1, r); x1 ^= x0; }
  TF_RND(13) TF_RND(15) TF_RND(26) TF_RND(6)
  x0 += ks1; x1 += ks2 + 1u;
  TF_RND(17) TF_RND(29) TF_RND(16) TF_RND(24)
  x0 += ks2; x1 += ks0 + 2u;
  TF_RND(13) TF_RND(15) TF_RND(26) TF_RND(6)
  x0 += ks0; x1 += ks1 + 3u;
  TF_RND(17) TF_RND(29) TF_RND(16) TF_RND(24)
  x0 += ks1; x1 += ks2 + 4u;
  TF_RND(13) TF_RND(15) TF_RND(26) TF_RND(6)
  x0 += ks2; x1 += ks0 + 5u;
#undef TF_RND
  o0 = x0; o1 = x1;
}

__device__ __forceinline__ float wave_sum(float v) {
  for (int off = 32; off; off >>= 1) v += __shfl_xor(v, off, 64);
  return v;
}
__device__ __forceinline__ float wave_max(float v) {
  for (int off = 32; off; off >>= 1) v = fmaxf(v, __shfl_xor(v, off, 64));
  return v;
}

// ---------------- K0: transpose the 64x64 weight matrices ----------------
__global__ __launch_bounds__(256) void transpose_w(
    const float* __restrict__ w1, const float* __restrict__ w2,
    const float* __restrict__ ra, const float* __restrict__ wa,
    const float* __restrict__ ma,
    float* __restrict__ w1T, float* __restrict__ w2T,
    float* __restrict__ raT, float* __restrict__ waT,
    float* __restrict__ maT) {
  int i = blockIdx.x * 256 + threadIdx.x;
  if (i < DD * DD) {
    int r = i >> 6, c = i & 63;
    w1T[c * DD + r] = w1[i];
    w2T[c * DD + r] = w2[i];
    raT[c * DD + r] = ra[i];
    waT[c * DD + r] = wa[i];
    maT[c * DD + r] = ma[i];
  }
}

// ---------------- K1: FUSED embed_gate + build_tables ----------------
// grid = NEBLK + NTBLK blocks, 256 threads. LDS = 17.4 KB -> 8 blocks/CU.
// GEMM path reads the B panel (waT/maT) directly from global: addresses are
// 16-thread-uniform and identical across blocks -> L1/L2 broadcast hits.
__global__ __launch_bounds__(256) void tables_embed(
    const int* __restrict__ uidx, const int* __restrict__ iidx,
    const float* __restrict__ emb,
    const float* __restrict__ w1T, const float* __restrict__ w2T,
    const float* __restrict__ b2, const float* __restrict__ bg,
    const float* __restrict__ waT, const float* __restrict__ wa_b,
    const float* __restrict__ maT,
    float* __restrict__ u_rev, float* __restrict__ i_rev,
    float* __restrict__ E1, float* __restrict__ E2) {
  __shared__ float smemA[DD * 68];   // 17408 B
  int tid = threadIdx.x;
  int bid = blockIdx.x;

  if (bid < NEBLK) {
    // ======== embed + gating (R6/R9 structure, bit-identical math) ========
    int* idxs = (int*)smemA;                       // 800 ints
    float (*us)[68] = (float(*)[68])(smemA + 800); // 16 x 68 floats
    int isItem = (bid >= 640);
    const int* src = isItem ? (iidx + (size_t)(bid - 640) * 16 * LL)
                            : (uidx + (size_t)bid * 16 * LL);
    for (int i = tid; i < 16 * LL; i += 256) idxs[i] = src[i];
    __syncthreads();
    int w = tid >> 6, lane = tid & 63;
    int grp = lane >> 4, q = lane & 15;
    int revl = w * 4 + grp;
    const int* myidx = idxs + revl * LL;
    float4 acc = {0.f, 0.f, 0.f, 0.f};
#pragma unroll
    for (int l = 0; l < LL; ++l) {                 // l-sequential (matches ref)
      int v = myidx[l];
      float4 e4 = *reinterpret_cast<const float4*>(&emb[(size_t)v * DD + q * 4]);
      acc.x += e4.x; acc.y += e4.y; acc.z += e4.z; acc.w += e4.w;
    }
    *reinterpret_cast<float4*>(&us[revl][q * 4]) = acc;
    __syncthreads();
    float4 d1 = {0.f, 0.f, 0.f, 0.f}, d2 = {0.f, 0.f, 0.f, 0.f};
    for (int e = 0; e < DD; ++e) {
      float xv = us[revl][e];                      // LDS broadcast
      float4 w1v = *reinterpret_cast<const float4*>(&w1T[e * DD + q * 4]);
      float4 w2v = *reinterpret_cast<const float4*>(&w2T[e * DD + q * 4]);
      d1.x += xv * w1v.x; d1.y += xv * w1v.y; d1.z += xv * w1v.z; d1.w += xv * w1v.w;
      d2.x += xv * w2v.x; d2.y += xv * w2v.y; d2.z += xv * w2v.z; d2.w += xv * w2v.w;
    }
    float4 b2v = *reinterpret_cast<const float4*>(&b2[q * 4]);
    float4 bgv = *reinterpret_cast<const float4*>(&bg[q * 4]);
    float4 val;
    val.x = 1.f / (1.f + expf(-d1.x)) + bgv.x * tanhf(d2.x + b2v.x);
    val.y = 1.f / (1.f + expf(-d1.y)) + bgv.y * tanhf(d2.y + b2v.y);
    val.z = 1.f / (1.f + expf(-d1.z)) + bgv.z * tanhf(d2.z + b2v.z);
    val.w = 1.f / (1.f + expf(-d1.w)) + bgv.w * tanhf(d2.w + b2v.w);
    int gid = bid * 16 + revl;
    int t = gid - isItem * (BB * RR);
    float* dst = isItem ? i_rev : u_rev;
    *reinterpret_cast<float4*>(&dst[(size_t)t * DD + q * 4]) = val;
    return;
  }

  // ======== table GEMM: E1 = relu(emb@waT+b), E2 = E1@maT ========
  float* A = smemA;   // AsT[k][w]; reused as RsT[d][w]
  int v0 = (bid - NEBLK) * 64;
  {
    int wr = tid & 63;             // vocab row within tile (bank stride 1)
    int qk = tid >> 6;             // 0..3
    int v = v0 + wr;
    for (int rep = 0; rep < 4; ++rep) {
      int k0 = rep * 16 + qk * 4;
      float4 e4 = {0.f, 0.f, 0.f, 0.f};
      if (v < VV) e4 = *reinterpret_cast<const float4*>(&emb[(size_t)v * DD + k0]);
      A[(k0 + 0) * 68 + wr] = e4.x;
      A[(k0 + 1) * 68 + wr] = e4.y;
      A[(k0 + 2) * 68 + wr] = e4.z;
      A[(k0 + 3) * 68 + wr] = e4.w;
    }
  }
  __syncthreads();
  int wq = tid & 15, dq = tid >> 4;
  float4 bias = *reinterpret_cast<const float4*>(&wa_b[dq * 4]);
  float acc[4][4];
#pragma unroll
  for (int i = 0; i < 4; ++i) {
    acc[i][0] = bias.x; acc[i][1] = bias.y; acc[i][2] = bias.z; acc[i][3] = bias.w;
  }
  for (int k = 0; k < DD; ++k) {
    float4 a4 = *reinterpret_cast<const float4*>(&A[k * 68 + wq * 4]);
    float4 b4 = *reinterpret_cast<const float4*>(&waT[k * DD + dq * 4]);  // global, L1-hot
    float av[4] = {a4.x, a4.y, a4.z, a4.w};
    float bv[4] = {b4.x, b4.y, b4.z, b4.w};
#pragma unroll
    for (int i = 0; i < 4; ++i)
#pragma unroll
      for (int j = 0; j < 4; ++j) acc[i][j] += av[i] * bv[j];
  }
#pragma unroll
  for (int i = 0; i < 4; ++i)
#pragma unroll
    for (int j = 0; j < 4; ++j) acc[i][j] = fmaxf(acc[i][j], 0.f);
#pragma unroll
  for (int i = 0; i < 4; ++i) {
    int v = v0 + wq * 4 + i;
    if (v < VV) {
      float4 r = {acc[i][0], acc[i][1], acc[i][2], acc[i][3]};
      *reinterpret_cast<float4*>(&E1[(size_t)v * DD + dq * 4]) = r;
    }
  }
  __syncthreads();
#pragma unroll
  for (int j = 0; j < 4; ++j)
#pragma unroll
    for (int i = 0; i < 4; ++i)
      A[(dq * 4 + j) * 68 + wq * 4 + i] = acc[i][j];
  __syncthreads();
  float acc2[4][4];
#pragma unroll
  for (int i = 0; i < 4; ++i)
#pragma unroll
    for (int j = 0; j < 4; ++j) acc2[i][j] = 0.f;
  for (int k = 0; k < DD; ++k) {
    float4 a4 = *reinterpret_cast<const float4*>(&A[k * 68 + wq * 4]);
    float4 b4 = *reinterpret_cast<const float4*>(&maT[k * DD + dq * 4]);  // global, L1-hot
    float av[4] = {a4.x, a4.y, a4.z, a4.w};
    float bv[4] = {b4.x, b4.y, b4.z, b4.w};
#pragma unroll
    for (int i = 0; i < 4; ++i)
#pragma unroll
      for (int j = 0; j < 4; ++j) acc2[i][j] += av[i] * bv[j];
  }
#pragma unroll
  for (int i = 0; i < 4; ++i) {
    int v = v0 + wq * 4 + i;
    if (v < VV) {
      float4 r = {acc2[i][0], acc2[i][1], acc2[i][2], acc2[i][3]};
      *reinterpret_cast<float4*>(&E2[(size_t)v * DD + dq * 4]) = r;
    }
  }
}

// ---------------- K2: FUSED coatt+selection+word+FM (one block per b) ----------------
// Phase 1: review co-attention + gumbel argmax (code bit-identical to R10's
//          coatt_rev_sel; sel stays in LDS).
// Phase 2: for p=0,1 word-level attention via E1/E2 tables -> xb[256] in LDS.
// Phase 3: FM head (wave 0), same math as R10 fm_head.
// LDS union: coatt needs 7340 floats, word needs 6828 -> 7340 + xb + sel4.
__global__ __launch_bounds__(256) void coatt_word_fm(
    const float* __restrict__ u_rev, const float* __restrict__ i_rev,
    const float* __restrict__ raT, const float* __restrict__ ra_b,
    const float* __restrict__ ra_M,
    const int* __restrict__ uidx, const int* __restrict__ iidx,
    const float* __restrict__ emb,
    const float* __restrict__ E1, const float* __restrict__ E2,
    const float* __restrict__ fm_v, const float* __restrict__ fm_w,
    const float* __restrict__ fm_b, float* __restrict__ out) {
  int b = blockIdx.x;
  int tid = threadIdx.x;
  __shared__ float smem[7340];
  __shared__ float xb[IN_DIM];
  __shared__ int sel4[4];

  { // ================= Phase 1: coatt + selection (bit-identical) =================
    float* ur = smem;            // 20*68
    float* ir = smem + 1360;
    float* uo = smem + 2720;
    float* io = smem + 4080;
    float* au = smem + 5440;
    float* sc = smem + 6800;     // 20*21
    float* rl = smem + 7220;     // 20
    float* cl = smem + 7240;     // 20
    float (*gval)[RR] = (float(*)[RR])(smem + 7260);  // 4*20
    for (int i = tid; i < RR * 16; i += 256) {
      int r = i >> 4, qq = i & 15;
      *reinterpret_cast<float4*>(&ur[r * 68 + qq * 4]) =
          *reinterpret_cast<const float4*>(&u_rev[(size_t)b * RR * DD + r * DD + qq * 4]);
      *reinterpret_cast<float4*>(&ir[r * 68 + qq * 4]) =
          *reinterpret_cast<const float4*>(&i_rev[(size_t)b * RR * DD + r * DD + qq * 4]);
    }
    __syncthreads();
    for (int s = tid; s < RR * 16; s += 256) {
      int u = s >> 4, q = s & 15;
      float4 bias = *reinterpret_cast<const float4*>(&ra_b[q * 4]);
      float4 a1 = bias, a2 = bias;
      for (int e = 0; e < DD; ++e) {
        float xu = ur[u * 68 + e];
        float xi = ir[u * 68 + e];
        float4 wv = *reinterpret_cast<const float4*>(&raT[e * DD + q * 4]);
        a1.x += xu * wv.x; a1.y += xu * wv.y; a1.z += xu * wv.z; a1.w += xu * wv.w;
        a2.x += xi * wv.x; a2.y += xi * wv.y; a2.z += xi * wv.z; a2.w += xi * wv.w;
      }
      a1.x = fmaxf(a1.x, 0.f); a1.y = fmaxf(a1.y, 0.f);
      a1.z = fmaxf(a1.z, 0.f); a1.w = fmaxf(a1.w, 0.f);
      a2.x = fmaxf(a2.x, 0.f); a2.y = fmaxf(a2.y, 0.f);
      a2.z = fmaxf(a2.z, 0.f); a2.w = fmaxf(a2.w, 0.f);
      *reinterpret_cast<float4*>(&uo[u * 68 + q * 4]) = a1;
      *reinterpret_cast<float4*>(&io[u * 68 + q * 4]) = a2;
    }
    __syncthreads();
    for (int s = tid; s < RR * 16; s += 256) {
      int u = s >> 4, q = s & 15;
      float4 a = {0.f, 0.f, 0.f, 0.f};
      for (int d2 = 0; d2 < DD; ++d2) {
        float xv = uo[u * 68 + d2];
        float4 mv = *reinterpret_cast<const float4*>(&ra_M[d2 * DD + q * 4]);
        a.x += xv * mv.x; a.y += xv * mv.y; a.z += xv * mv.z; a.w += xv * mv.w;
      }
      *reinterpret_cast<float4*>(&au[u * 68 + q * 4]) = a;
    }
    __syncthreads();
    for (int i = tid; i < RR * RR; i += 256) {
      int u = i / RR, v = i % RR;
      float a = 0.f;
      for (int e = 0; e < DD; ++e) a += au[u * 68 + e] * io[v * 68 + e];
      sc[u * 21 + v] = a;
    }
    __syncthreads();
    if (tid < RR) {
      float m = -INFINITY;
      for (int v = 0; v < RR; ++v) m = fmaxf(m, sc[tid * 21 + v]);
      rl[tid] = m;
    } else if (tid >= 64 && tid < 64 + RR) {
      int v = tid - 64;
      float m = -INFINITY;
      for (int u = 0; u < RR; ++u) m = fmaxf(m, sc[u * 21 + v]);
      cl[v] = m;
    }
    __syncthreads();
    if (tid < 4 * RR) {
      int n = tid / RR, r = tid % RR;
      uint32_t k0, k1, o0, o1;
      tf2x32(0u, 42u, 0u, (uint32_t)n, k0, k1);     // fold_in(key(42), n)
      int e = b * RR + r;
      tf2x32(k0, k1, 0u, (uint32_t)e, o0, o1);      // partitionable threefry
      uint32_t bits = o0 ^ o1;
      float u01 = __uint_as_float((bits >> 9) | 0x3f800000u) - 1.0f;
      const float TINY = 1.1754943508222875e-38f;
      float u = fmaxf(u01 + TINY, TINY);
      float g = -logf(-logf(u));
      gval[n][r] = ((n & 1) ? cl[r] : rl[r]) + g;
    }
    __syncthreads();
    if (tid < 4) {
      float best = -INFINITY; int arg = 0;
      for (int r = 0; r < RR; ++r) {                // serial: first-max tie-break
        float v = gval[tid][r];
        if (v > best) { best = v; arg = r; }
      }
      sel4[tid] = arg;
    }
  }

  // ================= Phase 2: word-level attention (p = 0, 1) =================
  float* E1u = smem;             // 50*65
  float* E2i = smem + 3250;
  float* ubar = smem + 6500;     // 64
  float* zbar = smem + 6564;     // 64
  float* rm = smem + 6628;       // 50
  float* cm = smem + 6678;       // 50
  int* uw = (int*)(smem + 6728); // 50 ints
  int* iw = (int*)(smem + 6778); // 50 ints
  int w = tid >> 6, lane = tid & 63;
  for (int p = 0; p < PP; ++p) {
    __syncthreads();             // previous phase fully done before LDS reuse
    int ru = sel4[2 * p], rv = sel4[2 * p + 1];
    if (tid < LL) uw[tid] = uidx[((size_t)b * RR + ru) * LL + tid];
    else if (tid >= 64 && tid < 64 + LL) iw[tid - 64] = iidx[((size_t)b * RR + rv) * LL + (tid - 64)];
    __syncthreads();
    for (int i = tid; i < LL * DD; i += 256) {
      int l = i >> 6, d = i & 63;
      E1u[l * 65 + d] = E1[(size_t)uw[l] * DD + d];
      E2i[l * 65 + d] = E2[(size_t)iw[l] * DD + d];
    }
    __syncthreads();
    if (tid < DD) {
      float s = 0.f;
      for (int l = 0; l < LL; ++l) s += E1u[l * 65 + tid];
      ubar[tid] = s / 50.f;
    } else if (tid < 128) {
      int d = tid - 64;
      float s = 0.f;
      for (int l = 0; l < LL; ++l) s += E2i[l * 65 + d];
      zbar[d] = s / 50.f;
    }
    __syncthreads();
    if (tid < LL) {
      float a = 0.f;
      for (int e = 0; e < DD; ++e) a += E1u[tid * 65 + e] * zbar[e];
      rm[tid] = a;
    } else if (tid >= 64 && tid < 64 + LL) {
      int lj = tid - 64;
      float a = 0.f;
      for (int e = 0; e < DD; ++e) a += ubar[e] * E2i[lj * 65 + e];
      cm[lj] = a;
    }
    __syncthreads();
    if (w == 0) {
      float v = (lane < LL) ? rm[lane] : -INFINITY;
      float m = wave_max(v);
      float ex = (lane < LL) ? expf(rm[lane] - m) : 0.f;
      float sm = wave_sum(ex);
      if (lane < LL) rm[lane] = ex / sm;
    } else if (w == 1) {
      float v = (lane < LL) ? cm[lane] : -INFINITY;
      float m = wave_max(v);
      float ex = (lane < LL) ? expf(cm[lane] - m) : 0.f;
      float sm = wave_sum(ex);
      if (lane < LL) cm[lane] = ex / sm;
    }
    __syncthreads();
    if (w == 0) {
      float a = 0.f;
      for (int l = 0; l < LL; ++l) a += rm[l] * emb[(size_t)uw[l] * DD + lane];
      xb[p * DD + lane] = a;
    } else if (w == 1) {
      float a = 0.f;
      for (int l = 0; l < LL; ++l) a += cm[l] * emb[(size_t)iw[l] * DD + lane];
      xb[2 * DD + p * DD + lane] = a;
    }
  }
  __syncthreads();

  // ================= Phase 3: FM head (wave 0; same math as before) =================
  if (tid < 64) {
    float4 xv4 = *reinterpret_cast<const float4*>(&xb[tid * 4]);
    float4 wv4 = *reinterpret_cast<const float4*>(&fm_w[tid * 4]);
    float xa[4] = {xv4.x, xv4.y, xv4.z, xv4.w};
    float wa[4] = {wv4.x, wv4.y, wv4.z, wv4.w};
    float lin = 0.f;
    float i1[KK], i2[KK];
#pragma unroll
    for (int k = 0; k < KK; ++k) { i1[k] = 0.f; i2[k] = 0.f; }
#pragma unroll
    for (int jj = 0; jj < 4; ++jj) {
      float xj = xa[jj];
      lin += xj * wa[jj];
      float x2 = xj * xj;
      const float* vr = fm_v + (size_t)(tid * 4 + jj) * KK;
#pragma unroll
      for (int k = 0; k < KK; ++k) {
        float v = vr[k];
        i1[k] += xj * v;
        i2[k] += x2 * (v * v);
      }
    }
    lin = wave_sum(lin);
    float pair = 0.f;
#pragma unroll
    for (int k = 0; k < KK; ++k) {
      float s1 = wave_sum(i1[k]);
      float s2 = wave_sum(i2[k]);
      pair += s1 * s1 - s2;
    }
    if (tid == 0) out[b] = (lin + fm_b[0]) + 0.5f * pair;
  }
}

extern "C" void kernel_launch(void* const* d_in, const int* in_sizes, int n_in,
                              void* d_out, int out_size, void* d_ws, size_t ws_size,
                              hipStream_t stream) {
  (void)in_sizes; (void)n_in; (void)out_size; (void)ws_size;
  const int*   user_reviews = (const int*)d_in[0];
  const int*   item_reviews = (const int*)d_in[1];
  const float* emb  = (const float*)d_in[2];
  const float* gw1  = (const float*)d_in[3];
  const float* gw2  = (const float*)d_in[4];
  const float* gb2  = (const float*)d_in[5];
  const float* gbg  = (const float*)d_in[6];
  const float* ra_w = (const float*)d_in[7];
  const float* ra_b = (const float*)d_in[8];
  const float* ra_M = (const float*)d_in[9];
  const float* wa_w = (const float*)d_in[10];
  const float* wa_b = (const float*)d_in[11];
  const float* wa_M = (const float*)d_in[12];
  const float* fm_v = (const float*)d_in[13];
  const float* fm_w = (const float*)d_in[14];
  const float* fm_b = (const float*)d_in[15];
  float* out = (float*)d_out;

  float* ws = (float*)d_ws;
  float* u_rev = ws;                        // B*R*D = 655360
  float* i_rev = u_rev + BB * RR * DD;      // 655360
  float* w1T   = i_rev + BB * RR * DD;      // 4096 each
  float* w2T   = w1T + DD * DD;
  float* raT   = w2T + DD * DD;
  float* waT   = raT + DD * DD;
  float* maT   = waT + DD * DD;
  float* E1    = maT + DD * DD;             // V*D = 3.2M
  float* E2    = E1 + (size_t)VV * DD;      // V*D = 3.2M

  transpose_w<<<dim3(16), dim3(256), 0, stream>>>(gw1, gw2, ra_w, wa_w, wa_M,
                                                  w1T, w2T, raT, waT, maT);
  tables_embed<<<dim3(NEBLK + NTBLK), dim3(256), 0, stream>>>(
      user_reviews, item_reviews, emb, w1T, w2T, gb2, gbg,
      waT, wa_b, maT, u_rev, i_rev, E1, E2);
  coatt_word_fm<<<dim3(BB), dim3(256), 0, stream>>>(
      u_rev, i_rev, raT, ra_b, ra_M,
      user_reviews, item_reviews, emb, E1, E2,
      fm_v, fm_w, fm_b, out);
}